// Round 1
// baseline (194.417 us; speedup 1.0000x reference)
//
#include <hip/hip_runtime.h>

// Weighted BCE over (N=4, C=3, 128^3) fp32.
// Identity (t in {0,1} exactly): t*log(p)+(1-t)*log(1-p) = log(t ? p : 1-p);
// count(t!=0) = sum(t) (float-exact below 2^24).
//
// R8 post-mortem: WIN -- nontemporal loads removed L2 line-install churn,
// partial 74.8 -> ~59 us (3.4 TB/s read). fillBuffer shows 6.8 TB/s
// write-only, so fabric has headroom.
// R10 theory: the runtime-trip-count loop caps per-wave ILP at 8 outstanding
// loads followed by a full vmcnt stall. Fast path for the fixed shape:
// fully unrolled, 16 nt-loads issued back-to-back per thread (256 B in
// flight/lane), contiguous 32 KB per-block windows (4 KB thread stride,
// not 1 MB), 4-way split accumulators to break the serial fadd chain.
// Predict: partial 3.4 -> >=5 TB/s read, ~59 -> ~38 us.

#define THREADS 256
#define BLOCKS_PER_SLAB 256
#define NSLABS 12            // N*C = 4*3
#define NCHAN 3
#define PAIRS 8              // float4 pairs per thread in the fast path
#define ENTRIES_PER_CHAN (4 * BLOCKS_PER_SLAB)   // 1024
#define EPT (ENTRIES_PER_CHAN / THREADS)         // stage-2 entries/thread = 4

typedef float v4f __attribute__((ext_vector_type(4)));

__device__ __forceinline__ v4f ntload(const v4f* __restrict__ p)
{
    return __builtin_nontemporal_load(p);
}

__global__ __launch_bounds__(THREADS) void bce_partial(
    const float* __restrict__ input,
    const float* __restrict__ target,
    float* __restrict__ psum,    // [3*1024]
    float* __restrict__ pcnt,    // [3*1024]
    int S4)                       // float4 per slab (524288)
{
    const int slab = blockIdx.x / BLOCKS_PER_SLAB;
    const int blk  = blockIdx.x % BLOCKS_PER_SLAB;
    const int c    = slab % NCHAN;              // block-uniform

    const v4f* __restrict__ in4 = (const v4f*)input  + (size_t)slab * S4;
    const v4f* __restrict__ tg4 = (const v4f*)target + (size_t)slab * S4;

    // 4-way split accumulators: serial-dependence chain length 8, not 32.
    float s0 = 0.0f, s1 = 0.0f, s2 = 0.0f, s3 = 0.0f;
    float n0 = 0.0f, n1 = 0.0f, n2 = 0.0f, n3 = 0.0f;

#define ACC4(pv, tv)                                                  \
    do {                                                              \
        float x0 = (tv)[0] != 0.0f ? (pv)[0] : (1.0f - (pv)[0]);      \
        float x1 = (tv)[1] != 0.0f ? (pv)[1] : (1.0f - (pv)[1]);      \
        float x2 = (tv)[2] != 0.0f ? (pv)[2] : (1.0f - (pv)[2]);      \
        float x3 = (tv)[3] != 0.0f ? (pv)[3] : (1.0f - (pv)[3]);      \
        s0 += fmaxf(__logf(x0), -100.0f);  n0 += (tv)[0];             \
        s1 += fmaxf(__logf(x1), -100.0f);  n1 += (tv)[1];             \
        s2 += fmaxf(__logf(x2), -100.0f);  n2 += (tv)[2];             \
        s3 += fmaxf(__logf(x3), -100.0f);  n3 += (tv)[3];             \
    } while (0)

    if (S4 == THREADS * PAIRS * BLOCKS_PER_SLAB) {
        // Fast path (the actual shape): compile-time trip count, contiguous
        // 32 KB window per block per stream, all 16 loads issued up front.
        const int base = blk * (THREADS * PAIRS) + (int)threadIdx.x;
        v4f p[PAIRS], t[PAIRS];
#pragma unroll
        for (int j = 0; j < PAIRS; ++j) {
            p[j] = ntload(in4 + base + j * THREADS);
            t[j] = ntload(tg4 + base + j * THREADS);
        }
#pragma unroll
        for (int j = 0; j < PAIRS; ++j)
            ACC4(p[j], t[j]);
    } else {
        // Generic fallback (unused for the benchmarked shape).
        const int stride = BLOCKS_PER_SLAB * THREADS;
        for (int i = blk * THREADS + (int)threadIdx.x; i < S4; i += stride) {
            v4f p = ntload(in4 + i);
            v4f t = ntload(tg4 + i);
            ACC4(p, t);
        }
    }
#undef ACC4

    float lsum = (s0 + s1) + (s2 + s3);
    float lcnt = (n0 + n1) + (n2 + n3);

    // wave (64-lane) reduction
#pragma unroll
    for (int off = 32; off > 0; off >>= 1) {
        lsum += __shfl_down(lsum, off, 64);
        lcnt += __shfl_down(lcnt, off, 64);
    }

    __shared__ float wsum[THREADS / 64];
    __shared__ float wcnt[THREADS / 64];
    const int lane = threadIdx.x & 63;
    const int wave = threadIdx.x >> 6;
    if (lane == 0) { wsum[wave] = lsum; wcnt[wave] = lcnt; }
    __syncthreads();
    if (threadIdx.x == 0) {
        float s = 0.0f, n = 0.0f;
#pragma unroll
        for (int w = 0; w < THREADS / 64; ++w) { s += wsum[w]; n += wcnt[w]; }
        const int e = c * ENTRIES_PER_CHAN + (slab / NCHAN) * BLOCKS_PER_SLAB + blk;
        psum[e] = s;          // plain stores, distinct addresses: NO atomics
        pcnt[e] = n;
    }
}

__global__ __launch_bounds__(THREADS) void bce_final(
    const float* __restrict__ psum,
    const float* __restrict__ pcnt,
    float* __restrict__ out,
    float per_chan_total)
{
    const int tid = (int)threadIdx.x;
    float s[NCHAN], n[NCHAN];
#pragma unroll
    for (int c = 0; c < NCHAN; ++c) {
        s[c] = 0.0f; n[c] = 0.0f;
#pragma unroll
        for (int e = 0; e < EPT; ++e) {
            const int b = c * ENTRIES_PER_CHAN + e * THREADS + tid;
            s[c] += psum[b];
            n[c] += pcnt[b];
        }
    }
#pragma unroll
    for (int off = 32; off > 0; off >>= 1) {
#pragma unroll
        for (int c = 0; c < NCHAN; ++c) {
            s[c] += __shfl_down(s[c], off, 64);
            n[c] += __shfl_down(n[c], off, 64);
        }
    }
    __shared__ float ws[THREADS / 64][NCHAN], wn[THREADS / 64][NCHAN];
    const int lane = tid & 63, wave = tid >> 6;
    if (lane == 0) {
#pragma unroll
        for (int c = 0; c < NCHAN; ++c) { ws[wave][c] = s[c]; wn[wave][c] = n[c]; }
    }
    __syncthreads();
    if (tid == 0) {
        float acc = 0.0f;
#pragma unroll
        for (int c = 0; c < NCHAN; ++c) {
            float ssum = 0.0f, ncnt = 0.0f;
#pragma unroll
            for (int w = 0; w < THREADS / 64; ++w) { ssum += ws[w][c]; ncnt += wn[w][c]; }
            float w8  = (ncnt > 0.0f) ? (per_chan_total / fmaxf(ncnt, 1.0f)) : 1000.0f;
            float bce = -(ssum / per_chan_total);
            acc += w8 * bce;
        }
        out[0] = acc / (float)NCHAN;
    }
}

extern "C" void kernel_launch(void* const* d_in, const int* in_sizes, int n_in,
                              void* d_out, int out_size, void* d_ws, size_t ws_size,
                              hipStream_t stream)
{
    const float* input  = (const float*)d_in[0];
    const float* target = (const float*)d_in[1];
    float*       out    = (float*)d_out;

    const int nentry = NCHAN * ENTRIES_PER_CHAN;          // 3072
    float* psum = (float*)d_ws;
    float* pcnt = (float*)d_ws + nentry;

    const long long total = (long long)in_sizes[0];        // 25,165,824
    const int       S4    = (int)(total / (NSLABS * 4));    // 524,288
    const float     M     = (float)(total / NCHAN);         // 8,388,608

    bce_partial<<<NSLABS * BLOCKS_PER_SLAB, THREADS, 0, stream>>>(
        input, target, psum, pcnt, S4);
    bce_final<<<1, THREADS, 0, stream>>>(psum, pcnt, out, M);
}